// Round 2
// 96.813 us; speedup vs baseline: 1.0162x; 1.0162x over previous
//
#include <hip/hip_runtime.h>
#include <hip/hip_fp16.h>
#include <math.h>

typedef _Float16 half8 __attribute__((ext_vector_type(8)));
typedef float f32x4 __attribute__((ext_vector_type(4)));

// prefix-parity nibble: bit k = parity of bits 0..k of 4-bit x
__device__ __forceinline__ int pfx4(int x) {
    return (x ^ (x << 1) ^ (x << 2) ^ (x << 3)) & 15;
}

// ---------- Fused kernel: qparam (U3 build) + MFMA statevector sim ----------
__global__ __attribute__((amdgpu_flat_work_group_size(256, 256), amdgpu_waves_per_eu(4, 4)))
void qreup_kernel(const float* __restrict__ x, const float* __restrict__ rw,
                  const float* __restrict__ rb,
                  const float* __restrict__ w1, const float* __restrict__ b1,
                  const float* __restrict__ w2, const float* __restrict__ b2,
                  float* __restrict__ out)
{
    __shared__ __align__(16) char lds[32768];     // 2 x 16KB rotating buffers
    char* const wl = lds;                         // W planes (dead after A-frag load)

    const int t = threadIdx.x;
    const int b = blockIdx.x;
    const int l15 = t & 15, q = (t >> 4) & 3, wv = t >> 6;

    // ---- fused qparam: 12 threads build U3 matrices into uL (aliases buf1,
    //      which is first written only at G0-L0 store, after W-build consumed uL)
    float* const uL = (float*)(lds + 16384);
    if (t < 12) {
        const float4 xv = ((const float4*)x)[b * 12 + t];
        float prm[3];
        #pragma unroll
        for (int p = 0; p < 3; ++p) {
            const float4 wvv = ((const float4*)rw)[t * 3 + p];
            prm[p] = rb[t * 3 + p] + wvv.x * xv.x + wvv.y * xv.y + wvv.z * xv.z + wvv.w * xv.w;
        }
        float st_, ct_; sincosf(0.5f * prm[0], &st_, &ct_);
        float sp_, cp_; sincosf(prm[1], &sp_, &cp_);
        float sl_, cl_; sincosf(prm[2], &sl_, &cl_);
        const float cpl = cp_ * cl_ - sp_ * sl_;
        const float spl = sp_ * cl_ + cp_ * sl_;
        ((float4*)uL)[t * 2]     = make_float4(ct_, 0.0f, -cl_ * st_, -sl_ * st_);
        ((float4*)uL)[t * 2 + 1] = make_float4(cp_ * st_, sp_ * st_, cpl * ct_, spl * ct_);
    }
    __syncthreads();

    // ---- Build W_g = tensor product of 4 U3s; hi/lo f16 planes (r15-verified)
    {
        const int mp = t >> 4, mm = t & 15;
        #pragma unroll
        for (int g = 0; g < 3; ++g) {
            const float* p0 = uL + g * 32 + ((mp & 1) * 4 + (mm & 1) * 2);
            float wr = p0[0], wi = p0[1];
            #pragma unroll
            for (int bq = 1; bq < 4; ++bq) {
                const float* p = uL + g * 32 + bq * 8 + ((mp >> bq) & 1) * 4 + ((mm >> bq) & 1) * 2;
                const float br = p[0], bi = p[1];
                const float nr = wr * br - wi * bi, ni = wr * bi + wi * br;
                wr = nr; wi = ni;
            }
            const _Float16 hr = (_Float16)wr, hi_ = (_Float16)wi;
            const _Float16 lr = (_Float16)(wr - (float)hr), li = (_Float16)(wi - (float)hi_);
            union { _Float16 h[2]; unsigned int u; } ph, pl_;
            ph.h[0] = hr;  ph.h[1] = hi_;
            pl_.h[0] = lr; pl_.h[1] = li;
            *(unsigned int*)(wl + g * 2048 +        mp * 64 + mm * 4) = ph.u;
            *(unsigned int*)(wl + g * 2048 + 1024 + mp * 64 + mm * 4) = pl_.u;
        }
    }
    __syncthreads();

    // ---- A-fragments (r15-verified): re={Re,-Im}, im={Im,Re}, hi/lo split
    half8 ArH[3], ArL[3], AiH[3], AiL[3];
    #pragma unroll
    for (int g = 0; g < 3; ++g) {
        #pragma unroll
        for (int hl = 0; hl < 2; ++hl) {
            int4 raw = *(const int4*)(wl + g * 2048 + hl * 1024 + l15 * 64 + q * 16);
            int re4[4], im4[4];
            int rr[4] = {raw.x, raw.y, raw.z, raw.w};
            #pragma unroll
            for (int i = 0; i < 4; ++i) {
                re4[i] = rr[i] ^ 0x80000000;
                im4[i] = (int)(((unsigned)rr[i] >> 16) | ((unsigned)rr[i] << 16));
            }
            half8 hre, him;
            __builtin_memcpy(&hre, re4, 16);
            __builtin_memcpy(&him, im4, 16);
            if (hl == 0) { ArH[g] = hre; AiH[g] = him; }
            else         { ArL[g] = hre; AiL[g] = him; }
        }
    }

    const int Ml = pfx4(l15);            // B0-store M nibble (prefix parities of l15)
    const int piL = (Ml >> 3) & 1;       // parity(l15)

    float A0 = 0.f, AT0 = 0.f, AT01 = 0.f, AR0 = 0.f, AR01 = 0.f;
    char* rbuf = lds;                    // pass p reads buf[p&1]
    char* wbuf = lds + 16384;

    #pragma unroll 1
    for (int L = 0; L < 3; ++L) {
        // ================= pass G0 =================
        if (L) __syncthreads();
        #pragma unroll
        for (int T = 0; T < 4; ++T) {
            const int tt = wv * 4 + T;
            half8 bfr;
            if (L == 0) {
                half8 z = {};
                if (t == 0 && T == 0) z[0] = (_Float16)1.0f;
                bfr = z;
            } else {
                // B0 load (CNOT folded via prefix-parity layout); nu = 16tt+l15
                const int nu = 16 * tt + l15;
                const int al = ((l15 >> 1) & 1) | ((((l15 >> 1) ^ (l15 >> 2)) & 1) << 1);
                const int be = ((tt >> 1) ^ (tt >> 2)) & 1;
                int4 raw = *(const int4*)(rbuf + 64 * (nu ^ be) + 16 * (q ^ al));
                if (tt & 8) {            // wave-uniform within-block pair swap
                    int tmp = raw.x; raw.x = raw.y; raw.y = tmp;
                    tmp = raw.z; raw.z = raw.w; raw.w = tmp;
                }
                __builtin_memcpy(&bfr, &raw, 16);
            }
            f32x4 cre = {0.f,0.f,0.f,0.f}, cim = {0.f,0.f,0.f,0.f};
            cre = __builtin_amdgcn_mfma_f32_16x16x32_f16(ArH[0], bfr, cre, 0, 0, 0);
            cre = __builtin_amdgcn_mfma_f32_16x16x32_f16(ArL[0], bfr, cre, 0, 0, 0);
            cim = __builtin_amdgcn_mfma_f32_16x16x32_f16(AiH[0], bfr, cim, 0, 0, 0);
            cim = __builtin_amdgcn_mfma_f32_16x16x32_f16(AiL[0], bfr, cim, 0, 0, 0);
            // B1 store: amp a[0:4)=4q+r, a[4:8)=l15, a[8:12)=tt
            // nu^bes = (4q+16tt) + (r^bes)  ->  4 stores at base+{0,64,128,192};
            // cndmask-reorder values so offsets are immediates (ds_write2-mergeable)
            const int als = q ^ ((tt >> 1) & 3);
            const int bes = (tt ^ q) & 1;
            const int D = 4 * (l15 ^ (als << 2));
            unsigned p4[4];
            #pragma unroll
            for (int r = 0; r < 4; ++r) {
                __half2 hp = __floats2half2_rn(cre[r], cim[r]);
                p4[r] = *(unsigned int*)&hp;
            }
            char* rowb = wbuf + 64 * (4 * q + 16 * tt) + D;
            const unsigned s0 = bes ? p4[1] : p4[0];
            const unsigned s1 = bes ? p4[0] : p4[1];
            const unsigned s2 = bes ? p4[3] : p4[2];
            const unsigned s3 = bes ? p4[2] : p4[3];
            *(unsigned int*)(rowb      ) = s0;
            *(unsigned int*)(rowb +  64) = s1;
            *(unsigned int*)(rowb + 128) = s2;
            *(unsigned int*)(rowb + 192) = s3;
        }
        { char* tmp = rbuf; rbuf = wbuf; wbuf = tmp; }

        // ================= pass G1 =================
        // T-paired: (tt, tt+1) share als/bes/D and their store rows differ by
        // exactly 64B -> paired same-base stores (ds_write2-mergeable)
        __syncthreads();
        #pragma unroll
        for (int Tp = 0; Tp < 2; ++Tp) {
            unsigned pe[4], po[4];
            #pragma unroll
            for (int hf = 0; hf < 2; ++hf) {
                const int T = Tp * 2 + hf;
                const int tt = wv * 4 + T;
                // B1 load: nu = tt + 16*l15 (lane split l15=a[8:12), tt=a[0:4))
                const int nu = tt + 16 * l15;
                const int al = ((tt >> 2) & 3) ^ ((l15 >> 1) & 3);
                const int be = (l15 ^ (tt >> 2)) & 1;
                int4 raw = *(const int4*)(rbuf + 64 * (nu ^ be) + 16 * (q ^ al));
                half8 bfr; __builtin_memcpy(&bfr, &raw, 16);
                f32x4 cre = {0.f,0.f,0.f,0.f}, cim = {0.f,0.f,0.f,0.f};
                cre = __builtin_amdgcn_mfma_f32_16x16x32_f16(ArH[1], bfr, cre, 0, 0, 0);
                cre = __builtin_amdgcn_mfma_f32_16x16x32_f16(ArL[1], bfr, cre, 0, 0, 0);
                cim = __builtin_amdgcn_mfma_f32_16x16x32_f16(AiH[1], bfr, cim, 0, 0, 0);
                cim = __builtin_amdgcn_mfma_f32_16x16x32_f16(AiL[1], bfr, cim, 0, 0, 0);
                #pragma unroll
                for (int r = 0; r < 4; ++r) {
                    __half2 hp = __floats2half2_rn(cre[r], cim[r]);
                    if (hf == 0) pe[r] = *(unsigned int*)&hp;
                    else         po[r] = *(unsigned int*)&hp;
                }
            }
            // B2 store: amp a[0:4)=tt, a[4:8)=4q+r, a[8:12)=l15
            const int tt0 = wv * 4 + Tp * 2;
            const int als = ((tt0 >> 1) & 3) ^ q;   // tt0>>1 == tt1>>1
            const int bes = q & 1;
            const int D = 4 * (l15 ^ (als << 2));
            #pragma unroll
            for (int r = 0; r < 4; ++r) {
                char* base = wbuf + 64 * (tt0 + 16 * (4 * q + r)) + D;
                const unsigned lo = bes ? po[r] : pe[r];
                const unsigned hi = bes ? pe[r] : po[r];
                *(unsigned int*)(base     ) = lo;
                *(unsigned int*)(base + 64) = hi;
            }
        }
        { char* tmp = rbuf; rbuf = wbuf; wbuf = tmp; }

        // ================= pass G2 =================
        __syncthreads();
        #pragma unroll
        for (int T = 0; T < 4; ++T) {
            const int tt = wv * 4 + T;
            // B2 load: nu = l15 + 16*tt (lane split l15=a[0:4), tt=a[4:8))
            const int nu = l15 + 16 * tt;
            const int al = ((l15 >> 1) & 3) ^ ((tt >> 2) & 3);
            const int be = (tt >> 2) & 1;
            int4 raw = *(const int4*)(rbuf + 64 * (nu ^ be) + 16 * (q ^ al));
            half8 bfr; __builtin_memcpy(&bfr, &raw, 16);
            f32x4 cre = {0.f,0.f,0.f,0.f}, cim = {0.f,0.f,0.f,0.f};
            cre = __builtin_amdgcn_mfma_f32_16x16x32_f16(ArH[2], bfr, cre, 0, 0, 0);
            cre = __builtin_amdgcn_mfma_f32_16x16x32_f16(ArL[2], bfr, cre, 0, 0, 0);
            cim = __builtin_amdgcn_mfma_f32_16x16x32_f16(AiH[2], bfr, cim, 0, 0, 0);
            cim = __builtin_amdgcn_mfma_f32_16x16x32_f16(AiL[2], bfr, cim, 0, 0, 0);
            if (L < 2) {
                // B0 scatter-store via prefix parities: u[0:4)=l15, u[4:8)=tt, u[8:12)=4q+r
                const int taub = pfx4(tt);
                const int lowH = (piL ? 15 : 0) ^ taub;      // H0..H3
                const int s    = (lowH >> 3) & 1;            // pi ^ tau3
                const int als  = ((lowH >> 1) & 1) | ((((lowH >> 1) ^ (lowH >> 2)) & 1) << 1);
                const int bes  = q & 1;                      // H5^H6
                const int D = 4 * (Ml ^ (als << 2));
                #pragma unroll
                for (int r = 0; r < 4; ++r) {
                    const int rho = pfx4(4 * q + r);
                    const int H = lowH | (((s ? 15 : 0) ^ rho) << 4);
                    __half2 hp = __floats2half2_rn(cre[r], cim[r]);
                    *(unsigned int*)(wbuf + 64 * (H ^ bes) + D) = *(unsigned int*)&hp;
                }
            } else {
                // fold final CNOT + measurement (r15-verified); a = l15|tt<<4|(4q+r)<<8
                const int sT0 = T & 1, sT01 = (T ^ (T >> 1)) & 1;
                #pragma unroll
                for (int r = 0; r < 4; ++r) {
                    const float pr = cre[r] * cre[r] + cim[r] * cim[r];
                    A0 += pr;
                    AT0  += sT0 ? -pr : pr;
                    AT01 += sT01 ? -pr : pr;
                    AR0  += (sT01 ^ (r & 1)) ? -pr : pr;
                    AR01 += (sT01 ^ ((r ^ (r >> 1)) & 1)) ? -pr : pr;
                }
            }
        }
        { char* tmp = rbuf; rbuf = wbuf; wbuf = tmp; }
    }

    // ---- per-thread signed sums -> zp[12] (r15-verified)
    const int pl = __popc(l15) & 1;
    const int wv0 = wv & 1, wv1 = (wv >> 1) & 1, wv01 = wv0 ^ wv1;
    const int q0 = q & 1, q1 = (q >> 1) & 1;
    float zp[12];
    zp[1] = (__popc(l15 & 3) & 1) ? -A0 : A0;
    zp[2] = (__popc(l15 & 7) & 1) ? -A0 : A0;
    zp[3] = pl ? -A0 : A0;
    zp[4] = pl ? -AT0 : AT0;
    zp[5] = pl ? -AT01 : AT01;
    zp[6] = (pl ^ wv0) ? -AT01 : AT01;
    zp[7] = (pl ^ wv0 ^ wv1) ? -AT01 : AT01;
    zp[8] = (pl ^ wv01) ? -AR0 : AR0;
    zp[9] = (pl ^ wv01) ? -AR01 : AR01;
    zp[10] = (pl ^ wv01 ^ q0) ? -AR01 : AR01;
    zp[11] = (pl ^ wv01 ^ q0 ^ q1) ? -AR01 : AR01;
    zp[0]  = ((l15 & 1) ^ pl ^ wv01 ^ q0 ^ q1) ? -AR01 : AR01;

    #pragma unroll
    for (int i = 0; i < 12; ++i) {
        float vv = zp[i];
        #pragma unroll
        for (int off = 32; off > 0; off >>= 1)
            vv += __shfl_xor(vv, off, 64);
        zp[i] = vv;
    }

    // ---- epilogue (verified), aliasing LDS
    __syncthreads();
    float* stf  = (float*)lds;
    float* zred = stf;        // [4][12]
    float* qzs  = stf + 48;   // [12]
    float* hbuf = stf + 64;   // [64]

    if ((t & 63) == 0) {
        #pragma unroll
        for (int i = 0; i < 12; ++i) zred[wv * 12 + i] = zp[i];
    }
    __syncthreads();
    if (t < 12)
        qzs[t] = zred[t] + zred[12 + t] + zred[24 + t] + zred[36 + t];
    __syncthreads();

    if (t < 64) {
        float acc = b1[t];
        #pragma unroll
        for (int i = 0; i < 12; ++i) acc += qzs[i] * w1[t * 12 + i];
        hbuf[t] = fmaxf(acc, 0.0f);
    }
    __syncthreads();
    float acc = b2[t];
    #pragma unroll 4
    for (int k4 = 0; k4 < 16; ++k4) {
        const float4 wvv = ((const float4*)w2)[t * 16 + k4];
        acc += wvv.x * hbuf[k4 * 4 + 0] + wvv.y * hbuf[k4 * 4 + 1]
             + wvv.z * hbuf[k4 * 4 + 2] + wvv.w * hbuf[k4 * 4 + 3];
    }
    out[b * 256 + t] = acc;
}

extern "C" void kernel_launch(void* const* d_in, const int* in_sizes, int n_in,
                              void* d_out, int out_size, void* d_ws, size_t ws_size,
                              hipStream_t stream) {
    const float* x  = (const float*)d_in[0];
    const float* rw = (const float*)d_in[1];
    const float* rb = (const float*)d_in[2];
    const float* w1 = (const float*)d_in[3];
    const float* b1 = (const float*)d_in[4];
    const float* w2 = (const float*)d_in[5];
    const float* b2 = (const float*)d_in[6];
    float* out = (float*)d_out;
    (void)d_ws; (void)ws_size;

    // in_sizes reports ELEMENT counts (floats), not bytes — baseline used /48.
    const int batch = in_sizes[0] / 48;           // x is [B,48] f32
    qreup_kernel<<<batch, 256, 0, stream>>>(x, rw, rb, w1, b1, w2, b2, out);
}

// Round 4
// 93.576 us; speedup vs baseline: 1.0513x; 1.0346x over previous
//
#include <hip/hip_runtime.h>
#include <hip/hip_fp16.h>
#include <math.h>

typedef _Float16 half8 __attribute__((ext_vector_type(8)));
typedef float f32x4 __attribute__((ext_vector_type(4)));

// prefix-parity nibble: bit k = parity of bits 0..k of 4-bit x (linear over XOR)
__device__ __forceinline__ int pfx4(int x) {
    return (x ^ (x << 1) ^ (x << 2) ^ (x << 3)) & 15;
}

__device__ __forceinline__ float shx(float v, int m) { return __shfl_xor(v, m, 64); }

// ---------- Fused kernel: qparam (U3 build) + MFMA statevector sim ----------
// NOTE: the L loop MUST stay `#pragma unroll 1`. Full unroll (R3) produced a
// launch-order-dependent output divergence (post-timing check failed) despite
// all barriers being preserved — suspected compiler scheduling issue at 3x
// body scale. R2 with unroll 1 passed the identical harness.
__global__ __attribute__((amdgpu_flat_work_group_size(256, 256), amdgpu_waves_per_eu(4, 4)))
void qreup_kernel(const float* __restrict__ x, const float* __restrict__ rw,
                  const float* __restrict__ rb,
                  const float* __restrict__ w1, const float* __restrict__ b1,
                  const float* __restrict__ w2, const float* __restrict__ b2,
                  float* __restrict__ out)
{
    __shared__ __align__(16) char lds[32768];     // 2 x 16KB rotating buffers
    char* const wl = lds;                         // W planes (dead after A-frag load)

    const int t = threadIdx.x;
    const int b = blockIdx.x;
    const int l15 = t & 15, q = (t >> 4) & 3, wv = t >> 6;

    // ---- fused qparam: 12 threads build U3 matrices into uL (aliases buf1,
    //      which is first written only at G0-L0 store, after W-build consumed uL)
    float* const uL = (float*)(lds + 16384);
    if (t < 12) {
        const float4 xv = ((const float4*)x)[b * 12 + t];
        float prm[3];
        #pragma unroll
        for (int p = 0; p < 3; ++p) {
            const float4 wvv = ((const float4*)rw)[t * 3 + p];
            prm[p] = rb[t * 3 + p] + wvv.x * xv.x + wvv.y * xv.y + wvv.z * xv.z + wvv.w * xv.w;
        }
        float st_, ct_; sincosf(0.5f * prm[0], &st_, &ct_);
        float sp_, cp_; sincosf(prm[1], &sp_, &cp_);
        float sl_, cl_; sincosf(prm[2], &sl_, &cl_);
        const float cpl = cp_ * cl_ - sp_ * sl_;
        const float spl = sp_ * cl_ + cp_ * sl_;
        ((float4*)uL)[t * 2]     = make_float4(ct_, 0.0f, -cl_ * st_, -sl_ * st_);
        ((float4*)uL)[t * 2 + 1] = make_float4(cp_ * st_, sp_ * st_, cpl * ct_, spl * ct_);
    }
    __syncthreads();

    // ---- Build W_g = tensor product of 4 U3s; hi/lo f16 planes (r15-verified)
    {
        const int mp = t >> 4, mm = t & 15;
        #pragma unroll
        for (int g = 0; g < 3; ++g) {
            const float* p0 = uL + g * 32 + ((mp & 1) * 4 + (mm & 1) * 2);
            float wr = p0[0], wi = p0[1];
            #pragma unroll
            for (int bq = 1; bq < 4; ++bq) {
                const float* p = uL + g * 32 + bq * 8 + ((mp >> bq) & 1) * 4 + ((mm >> bq) & 1) * 2;
                const float br = p[0], bi = p[1];
                const float nr = wr * br - wi * bi, ni = wr * bi + wi * br;
                wr = nr; wi = ni;
            }
            const _Float16 hr = (_Float16)wr, hi_ = (_Float16)wi;
            const _Float16 lr = (_Float16)(wr - (float)hr), li = (_Float16)(wi - (float)hi_);
            union { _Float16 h[2]; unsigned int u; } ph, pl_;
            ph.h[0] = hr;  ph.h[1] = hi_;
            pl_.h[0] = lr; pl_.h[1] = li;
            *(unsigned int*)(wl + g * 2048 +        mp * 64 + mm * 4) = ph.u;
            *(unsigned int*)(wl + g * 2048 + 1024 + mp * 64 + mm * 4) = pl_.u;
        }
    }
    __syncthreads();

    // ---- A-fragments (r15-verified): re={Re,-Im}, im={Im,Re}, hi/lo split
    half8 ArH[3], ArL[3], AiH[3], AiL[3];
    #pragma unroll
    for (int g = 0; g < 3; ++g) {
        #pragma unroll
        for (int hl = 0; hl < 2; ++hl) {
            int4 raw = *(const int4*)(wl + g * 2048 + hl * 1024 + l15 * 64 + q * 16);
            int re4[4], im4[4];
            int rr[4] = {raw.x, raw.y, raw.z, raw.w};
            #pragma unroll
            for (int i = 0; i < 4; ++i) {
                re4[i] = rr[i] ^ 0x80000000;
                im4[i] = (int)(((unsigned)rr[i] >> 16) | ((unsigned)rr[i] << 16));
            }
            half8 hre, him;
            __builtin_memcpy(&hre, re4, 16);
            __builtin_memcpy(&him, im4, 16);
            if (hl == 0) { ArH[g] = hre; AiH[g] = him; }
            else         { ArL[g] = hre; AiL[g] = him; }
        }
    }

    const int Ml = pfx4(l15);            // B0-store M nibble (prefix parities of l15)
    const int piL = (Ml >> 3) & 1;       // parity(l15)

    float A0 = 0.f, AT0 = 0.f, AT01 = 0.f, AR0 = 0.f, AR01 = 0.f;
    char* rbuf = lds;                    // pass p reads buf[p&1]
    char* wbuf = lds + 16384;

    #pragma unroll 1
    for (int L = 0; L < 3; ++L) {
        // ================= pass G0 =================
        if (L) __syncthreads();
        #pragma unroll
        for (int T = 0; T < 4; ++T) {
            const int tt = wv * 4 + T;
            half8 bfr;
            if (L == 0) {
                half8 z = {};
                if (t == 0 && T == 0) z[0] = (_Float16)1.0f;
                bfr = z;
            } else {
                // B0 load (CNOT folded via prefix-parity layout); nu = 16tt+l15
                const int nu = 16 * tt + l15;
                const int al = ((l15 >> 1) & 1) | ((((l15 >> 1) ^ (l15 >> 2)) & 1) << 1);
                const int be = ((tt >> 1) ^ (tt >> 2)) & 1;
                int4 raw = *(const int4*)(rbuf + 64 * (nu ^ be) + 16 * (q ^ al));
                if (tt & 8) {            // wave-uniform within-block pair swap
                    int tmp = raw.x; raw.x = raw.y; raw.y = tmp;
                    tmp = raw.z; raw.z = raw.w; raw.w = tmp;
                }
                __builtin_memcpy(&bfr, &raw, 16);
            }
            f32x4 cre = {0.f,0.f,0.f,0.f}, cim = {0.f,0.f,0.f,0.f};
            cre = __builtin_amdgcn_mfma_f32_16x16x32_f16(ArH[0], bfr, cre, 0, 0, 0);
            cre = __builtin_amdgcn_mfma_f32_16x16x32_f16(ArL[0], bfr, cre, 0, 0, 0);
            cim = __builtin_amdgcn_mfma_f32_16x16x32_f16(AiH[0], bfr, cim, 0, 0, 0);
            cim = __builtin_amdgcn_mfma_f32_16x16x32_f16(AiL[0], bfr, cim, 0, 0, 0);
            // B1 store: amp a[0:4)=4q+r, a[4:8)=l15, a[8:12)=tt
            // nu^bes = (4q+16tt) + (r^bes)  ->  4 stores at base+{0,64,128,192};
            // cndmask-reorder values so offsets are immediates (ds_write2-mergeable)
            const int als = q ^ ((tt >> 1) & 3);
            const int bes = (tt ^ q) & 1;
            const int D = 4 * (l15 ^ (als << 2));
            unsigned p4[4];
            #pragma unroll
            for (int r = 0; r < 4; ++r) {
                __half2 hp = __floats2half2_rn(cre[r], cim[r]);
                p4[r] = *(unsigned int*)&hp;
            }
            char* rowb = wbuf + 64 * (4 * q + 16 * tt) + D;
            const unsigned s0 = bes ? p4[1] : p4[0];
            const unsigned s1 = bes ? p4[0] : p4[1];
            const unsigned s2 = bes ? p4[3] : p4[2];
            const unsigned s3 = bes ? p4[2] : p4[3];
            *(unsigned int*)(rowb      ) = s0;
            *(unsigned int*)(rowb +  64) = s1;
            *(unsigned int*)(rowb + 128) = s2;
            *(unsigned int*)(rowb + 192) = s3;
        }
        { char* tmp = rbuf; rbuf = wbuf; wbuf = tmp; }

        // ================= pass G1 =================
        // T-paired: (tt, tt+1) share als/bes/D and their store rows differ by
        // exactly 64B -> paired same-base stores (ds_write2-mergeable)
        __syncthreads();
        #pragma unroll
        for (int Tp = 0; Tp < 2; ++Tp) {
            unsigned pe[4], po[4];
            #pragma unroll
            for (int hf = 0; hf < 2; ++hf) {
                const int T = Tp * 2 + hf;
                const int tt = wv * 4 + T;
                // B1 load: nu = tt + 16*l15 (lane split l15=a[8:12), tt=a[0:4))
                const int nu = tt + 16 * l15;
                const int al = ((tt >> 2) & 3) ^ ((l15 >> 1) & 3);
                const int be = (l15 ^ (tt >> 2)) & 1;
                int4 raw = *(const int4*)(rbuf + 64 * (nu ^ be) + 16 * (q ^ al));
                half8 bfr; __builtin_memcpy(&bfr, &raw, 16);
                f32x4 cre = {0.f,0.f,0.f,0.f}, cim = {0.f,0.f,0.f,0.f};
                cre = __builtin_amdgcn_mfma_f32_16x16x32_f16(ArH[1], bfr, cre, 0, 0, 0);
                cre = __builtin_amdgcn_mfma_f32_16x16x32_f16(ArL[1], bfr, cre, 0, 0, 0);
                cim = __builtin_amdgcn_mfma_f32_16x16x32_f16(AiH[1], bfr, cim, 0, 0, 0);
                cim = __builtin_amdgcn_mfma_f32_16x16x32_f16(AiL[1], bfr, cim, 0, 0, 0);
                #pragma unroll
                for (int r = 0; r < 4; ++r) {
                    __half2 hp = __floats2half2_rn(cre[r], cim[r]);
                    if (hf == 0) pe[r] = *(unsigned int*)&hp;
                    else         po[r] = *(unsigned int*)&hp;
                }
            }
            // B2 store: amp a[0:4)=tt, a[4:8)=4q+r, a[8:12)=l15
            const int tt0 = wv * 4 + Tp * 2;
            const int als = ((tt0 >> 1) & 3) ^ q;   // tt0>>1 == tt1>>1
            const int bes = q & 1;
            const int D = 4 * (l15 ^ (als << 2));
            #pragma unroll
            for (int r = 0; r < 4; ++r) {
                char* base = wbuf + 64 * (tt0 + 16 * (4 * q + r)) + D;
                const unsigned lo = bes ? po[r] : pe[r];
                const unsigned hi = bes ? pe[r] : po[r];
                *(unsigned int*)(base     ) = lo;
                *(unsigned int*)(base + 64) = hi;
            }
        }
        { char* tmp = rbuf; rbuf = wbuf; wbuf = tmp; }

        // ================= pass G2 =================
        __syncthreads();
        if (L < 2) {
            // T-pairs (0,3),(1,2): lowH differs only in bit0 (pfx4 linearity),
            // s/als/bes/D identical -> store rows 64B apart, cndmask lo/hi.
            #pragma unroll
            for (int pr = 0; pr < 2; ++pr) {
                const int Ta = pr, Tb = 3 - pr;
                unsigned va[4], vb[4];
                #pragma unroll
                for (int hf = 0; hf < 2; ++hf) {
                    const int T = hf ? Tb : Ta;
                    const int tt = wv * 4 + T;
                    // B2 load: nu = l15 + 16*tt (lane split l15=a[0:4), tt=a[4:8))
                    const int nu = l15 + 16 * tt;
                    const int al = ((l15 >> 1) & 3) ^ ((tt >> 2) & 3);
                    const int be = (tt >> 2) & 1;
                    int4 raw = *(const int4*)(rbuf + 64 * (nu ^ be) + 16 * (q ^ al));
                    half8 bfr; __builtin_memcpy(&bfr, &raw, 16);
                    f32x4 cre = {0.f,0.f,0.f,0.f}, cim = {0.f,0.f,0.f,0.f};
                    cre = __builtin_amdgcn_mfma_f32_16x16x32_f16(ArH[2], bfr, cre, 0, 0, 0);
                    cre = __builtin_amdgcn_mfma_f32_16x16x32_f16(ArL[2], bfr, cre, 0, 0, 0);
                    cim = __builtin_amdgcn_mfma_f32_16x16x32_f16(AiH[2], bfr, cim, 0, 0, 0);
                    cim = __builtin_amdgcn_mfma_f32_16x16x32_f16(AiL[2], bfr, cim, 0, 0, 0);
                    #pragma unroll
                    for (int r = 0; r < 4; ++r) {
                        __half2 hp = __floats2half2_rn(cre[r], cim[r]);
                        if (hf == 0) va[r] = *(unsigned int*)&hp;
                        else         vb[r] = *(unsigned int*)&hp;
                    }
                }
                // B0 store via prefix parities: u[0:4)=l15, u[4:8)=tt, u[8:12)=4q+r
                const int tta  = wv * 4 + Ta;
                const int lowHa = (piL ? 15 : 0) ^ pfx4(tta);
                const int s    = (lowHa >> 3) & 1;
                const int als  = ((lowHa >> 1) & 1) | ((((lowHa >> 1) ^ (lowHa >> 2)) & 1) << 1);
                const int bes  = q & 1;
                const int D = 4 * (Ml ^ (als << 2));
                const int cb = (lowHa ^ bes) & 1;
                char* base = wbuf + 64 * ((lowHa ^ bes) & ~1) + D;
                #pragma unroll
                for (int r = 0; r < 4; ++r) {
                    const int hiN = (s ? 15 : 0) ^ pfx4(4 * q + r);
                    const unsigned lo = cb ? vb[r] : va[r];
                    const unsigned hi = cb ? va[r] : vb[r];
                    *(unsigned int*)(base + 1024 * hiN     ) = lo;
                    *(unsigned int*)(base + 1024 * hiN + 64) = hi;
                }
            }
        } else {
            #pragma unroll
            for (int T = 0; T < 4; ++T) {
                const int tt = wv * 4 + T;
                const int nu = l15 + 16 * tt;
                const int al = ((l15 >> 1) & 3) ^ ((tt >> 2) & 3);
                const int be = (tt >> 2) & 1;
                int4 raw = *(const int4*)(rbuf + 64 * (nu ^ be) + 16 * (q ^ al));
                half8 bfr; __builtin_memcpy(&bfr, &raw, 16);
                f32x4 cre = {0.f,0.f,0.f,0.f}, cim = {0.f,0.f,0.f,0.f};
                cre = __builtin_amdgcn_mfma_f32_16x16x32_f16(ArH[2], bfr, cre, 0, 0, 0);
                cre = __builtin_amdgcn_mfma_f32_16x16x32_f16(ArL[2], bfr, cre, 0, 0, 0);
                cim = __builtin_amdgcn_mfma_f32_16x16x32_f16(AiH[2], bfr, cim, 0, 0, 0);
                cim = __builtin_amdgcn_mfma_f32_16x16x32_f16(AiL[2], bfr, cim, 0, 0, 0);
                // fold final CNOT + measurement (r15-verified); a = l15|tt<<4|(4q+r)<<8
                const int sT0 = T & 1, sT01 = (T ^ (T >> 1)) & 1;
                #pragma unroll
                for (int r = 0; r < 4; ++r) {
                    const float pr2 = cre[r] * cre[r] + cim[r] * cim[r];
                    A0 += pr2;
                    AT0  += sT0 ? -pr2 : pr2;
                    AT01 += sT01 ? -pr2 : pr2;
                    AR0  += (sT01 ^ (r & 1)) ? -pr2 : pr2;
                    AR01 += (sT01 ^ ((r ^ (r >> 1)) & 1)) ? -pr2 : pr2;
                }
            }
        }
        { char* tmp = rbuf; rbuf = wbuf; wbuf = tmp; }
    }

    // ---- signed-butterfly Walsh reductions (replaces 12x plain reduce):
    // lane0 ends with sum_l (-1)^popc(lane&mask) * x_lane; wave-uniform signs
    // (wv bits) fold into the lane-0 zred write below.
    const int wv0 = wv & 1, wv1 = (wv >> 1) & 1, wv01 = wv0 ^ wv1;
    float v, tw;
    // A0 family: masks 3, 7, 15
    v = A0;
    v -= shx(v, 1);
    v -= shx(v, 2);
    tw = shx(v, 4);
    float a3 = v + tw, a7f = v - tw;
    tw = shx(a3, 8);  float S1 = a3 + tw;            // mask 3  -> zp[1]
    tw = shx(a7f, 8); float S2 = a7f + tw;           // mask 7  -> zp[2]
    float S3 = a7f - tw;                             // mask 15 -> zp[3]
    S1 += shx(S1, 16); S1 += shx(S1, 32);
    S2 += shx(S2, 16); S2 += shx(S2, 32);
    S3 += shx(S3, 16); S3 += shx(S3, 32);
    // mask-15 reductions
    float S4 = AT0, S5 = AT01, S8 = AR0;
    S4 -= shx(S4, 1); S4 -= shx(S4, 2); S4 -= shx(S4, 4); S4 -= shx(S4, 8);
    S4 += shx(S4, 16); S4 += shx(S4, 32);
    S5 -= shx(S5, 1); S5 -= shx(S5, 2); S5 -= shx(S5, 4); S5 -= shx(S5, 8);
    S5 += shx(S5, 16); S5 += shx(S5, 32);
    S8 -= shx(S8, 1); S8 -= shx(S8, 2); S8 -= shx(S8, 4); S8 -= shx(S8, 8);
    S8 += shx(S8, 16); S8 += shx(S8, 32);
    // AR01 family: masks 15, 31, 63, 62
    v = AR01;
    v -= shx(v, 2); v -= shx(v, 4); v -= shx(v, 8);  // bits 1,2,3 (all masks)
    tw = shx(v, 1);
    float U = v - tw;        // bit0 in mask (15,31,63)
    float W = v + tw;        // bit0 out (62)
    tw = shx(U, 16);
    float P = U + tw;        // bit4 out (15)
    float Q = U - tw;        // bit4 in (31,63)
    tw = shx(W, 16);
    float R = W - tw;        // 62 has bit4
    float S9 = P + shx(P, 32);                       // mask 15
    tw = shx(Q, 32);
    float S10 = Q + tw;                              // mask 31
    float S11 = Q - tw;                              // mask 63
    float S0 = R - shx(R, 32);                       // mask 62

    // ---- epilogue (verified), aliasing LDS
    __syncthreads();
    float* stf  = (float*)lds;
    float* zred = stf;        // [4][12]
    float* qzs  = stf + 48;   // [12]
    float* hbuf = stf + 64;   // [64]

    if ((t & 63) == 0) {
        float* zr = zred + wv * 12;
        zr[0]  = wv01 ? -S0  : S0;
        zr[1]  = S1;
        zr[2]  = S2;
        zr[3]  = S3;
        zr[4]  = S4;
        zr[5]  = S5;
        zr[6]  = wv0 ? -S5 : S5;
        zr[7]  = (wv0 ^ wv1) ? -S5 : S5;
        zr[8]  = wv01 ? -S8  : S8;
        zr[9]  = wv01 ? -S9  : S9;
        zr[10] = wv01 ? -S10 : S10;
        zr[11] = wv01 ? -S11 : S11;
    }
    __syncthreads();
    if (t < 12)
        qzs[t] = zred[t] + zred[12 + t] + zred[24 + t] + zred[36 + t];
    __syncthreads();

    if (t < 64) {
        float acc = b1[t];
        #pragma unroll
        for (int i = 0; i < 12; ++i) acc += qzs[i] * w1[t * 12 + i];
        hbuf[t] = fmaxf(acc, 0.0f);
    }
    __syncthreads();
    float acc = b2[t];
    #pragma unroll 4
    for (int k4 = 0; k4 < 16; ++k4) {
        const float4 wvv = ((const float4*)w2)[t * 16 + k4];
        acc += wvv.x * hbuf[k4 * 4 + 0] + wvv.y * hbuf[k4 * 4 + 1]
             + wvv.z * hbuf[k4 * 4 + 2] + wvv.w * hbuf[k4 * 4 + 3];
    }
    out[b * 256 + t] = acc;
}

extern "C" void kernel_launch(void* const* d_in, const int* in_sizes, int n_in,
                              void* d_out, int out_size, void* d_ws, size_t ws_size,
                              hipStream_t stream) {
    const float* x  = (const float*)d_in[0];
    const float* rw = (const float*)d_in[1];
    const float* rb = (const float*)d_in[2];
    const float* w1 = (const float*)d_in[3];
    const float* b1 = (const float*)d_in[4];
    const float* w2 = (const float*)d_in[5];
    const float* b2 = (const float*)d_in[6];
    float* out = (float*)d_out;
    (void)d_ws; (void)ws_size;

    // in_sizes reports ELEMENT counts (floats), not bytes.
    const int batch = in_sizes[0] / 48;           // x is [B,48] f32
    qreup_kernel<<<batch, 256, 0, stream>>>(x, rw, rb, w1, b1, w2, b2, out);
}